// Round 7
// baseline (289.434 us; speedup 1.0000x reference)
//
#include <hip/hip_runtime.h>
#include <hip/hip_bf16.h>

#define NN 50000
#define NE 600000
#define D 128
#define NREL 2

typedef __attribute__((ext_vector_type(8))) short bf16x8;   // 8 bf16 (4 VGPRs)
typedef __attribute__((ext_vector_type(4))) float f32x4;    // 4 fp32 acc

__device__ __forceinline__ float bf2f(short s) {
    return __uint_as_float(((unsigned int)(unsigned short)s) << 16);
}
__device__ __forceinline__ bf16x8 pack_bf8(const float* a) {
    union { bf16x8 v; __hip_bfloat162 h2[4]; } o;
#pragma unroll
    for (int i = 0; i < 4; i++)
        o.h2[i] = __float22bfloat162_rn(make_float2(a[2 * i], a[2 * i + 1]));
    return o.v;
}

// ---------------- per-relation in-degree (edge type recomputed on the fly) ----
__global__ void k_count(const float* __restrict__ attr,
                        const int* __restrict__ dst,
                        int* __restrict__ cnt, int E) {
    int i = blockIdx.x * blockDim.x + threadIdx.x;
    if (i >= E) return;
    float2 a = reinterpret_cast<const float2*>(attr)[i];
    int r = (a.y > a.x) ? 1 : 0;   // argmax, first-index tiebreak
    atomicAdd(&cnt[r * NN + dst[i]], 1);
}

__global__ void k_inv(const int* __restrict__ cnt, float* __restrict__ inv) {
    int i = blockIdx.x * blockDim.x + threadIdx.x;
    if (i >= NREL * NN) return;
    int c = cnt[i];
    inv[i] = 1.0f / (float)(c > 1 ? c : 1);
}

// ---------------- bucket allocator: off/cur = fetch_add(total, cnt[i]) -------
__global__ void k_alloc(const int* __restrict__ cnt, int* __restrict__ off,
                        int* __restrict__ cur, int* __restrict__ total) {
    int i = blockIdx.x * blockDim.x + threadIdx.x;
    if (i >= NREL * NN) return;
    int o = atomicAdd(total, cnt[i]);    // wave-coalesced by atomic optimizer
    off[i] = o;
    cur[i] = o;
}

// ---------------- fill CSR: srcs[pos] = src[e], bucketed by (rel,dst) --------
__global__ void k_fill(const float* __restrict__ attr,
                       const int* __restrict__ src, const int* __restrict__ dst,
                       int* __restrict__ cursor, int* __restrict__ srcs, int E) {
    int i = blockIdx.x * blockDim.x + threadIdx.x;
    if (i >= E) return;
    float2 a = reinterpret_cast<const float2*>(attr)[i];
    int r = (a.y > a.x) ? 1 : 0;
    int pos = atomicAdd(&cursor[r * NN + dst[i]], 1);
    srcs[pos] = src[i];
}

// ---------------- weights: transpose + concat + bf16 ----------------
// wt[0:16384)                  : proj  Wtp[n][k] = Wf[k][n]          (K=128)
// wt[16384 + l*49152 + n*384+k]: layer l, k<128 root, <256 W0, else W1
__global__ void k_prep_w(const float* __restrict__ Wf,
                         const float* __restrict__ cw,
                         const float* __restrict__ cr,
                         __hip_bfloat16* __restrict__ wt) {
    int idx = blockIdx.x * blockDim.x + threadIdx.x;
    if (idx >= 16384 + 3 * 49152) return;
    float v;
    if (idx < 16384) {
        int n = idx >> 7, k = idx & 127;
        v = Wf[k * 128 + n];
    } else {
        int j = idx - 16384;
        int l = j / 49152; j %= 49152;
        int n = j / 384, k = j % 384;
        if (k < 128)      v = cr[((size_t)l * 128 + k) * 128 + n];
        else if (k < 256) v = cw[((size_t)(l * 2 + 0) * 128 + (k - 128)) * 128 + n];
        else              v = cw[((size_t)(l * 2 + 1) * 128 + (k - 256)) * 128 + n];
    }
    wt[idx] = __float2bfloat16(v);
}

// ---------------- proj GEMM: h0 = relu(x_f32 @ Wtp^T + bf), bf16 out ---------
// BM=128, 4 waves, A read f32 direct from global, converted in-register.
__global__ __launch_bounds__(256)
void k_gemm_proj(const float* __restrict__ X,
                 const __hip_bfloat16* __restrict__ Wt,   // [128][128]
                 const float* __restrict__ bias,
                 __hip_bfloat16* __restrict__ out, int N) {
    __shared__ uint4 sB4[1024];            // 16 KB
    char* sB = (char*)sB4;
    const int tid = threadIdx.x;
    const int w = tid >> 6;
    const int l16 = tid & 15, lg = (tid & 63) >> 4;

    f32x4 acc[2][8];
#pragma unroll
    for (int m = 0; m < 2; m++)
#pragma unroll
        for (int n = 0; n < 8; n++) acc[m][n] = (f32x4)(0.f);

    const int row0 = blockIdx.x * 128;
#pragma unroll
    for (int kb = 0; kb < 2; ++kb) {
        bf16x8 afr[2][2];
#pragma unroll
        for (int mb = 0; mb < 2; ++mb)
#pragma unroll
            for (int kk = 0; kk < 2; ++kk) {
                int r = row0 + w * 32 + mb * 16 + l16;
                if (r >= N) r = N - 1;
                const float* p = X + (size_t)r * D + kb * 64 + kk * 32 + lg * 8;
                float4 u0 = reinterpret_cast<const float4*>(p)[0];
                float4 u1 = reinterpret_cast<const float4*>(p)[1];
                float t[8] = {u0.x, u0.y, u0.z, u0.w, u1.x, u1.y, u1.z, u1.w};
                afr[mb][kk] = pack_bf8(t);
            }
        __syncthreads();
        {
            int trow = tid >> 3, tb = (tid & 7) * 16;
#pragma unroll
            for (int p = 0; p < 4; ++p) {
                int rr = trow + p * 32;
                uint4 v = *reinterpret_cast<const uint4*>(
                    (const char*)(Wt + (size_t)rr * 128 + kb * 64) + tb);
                *reinterpret_cast<uint4*>(sB + rr * 128 + (tb ^ ((rr & 7) << 4))) = v;
            }
        }
        __syncthreads();
#pragma unroll
        for (int kk = 0; kk < 2; ++kk)
#pragma unroll
            for (int nb = 0; nb < 8; ++nb) {
                int brow = nb * 16 + l16;
                int bcol = kk * 64 + lg * 16;
                bf16x8 bfr = *reinterpret_cast<const bf16x8*>(
                    sB + brow * 128 + (bcol ^ ((brow & 7) << 4)));
                acc[0][nb] = __builtin_amdgcn_mfma_f32_16x16x32_bf16(
                    afr[0][kk], bfr, acc[0][nb], 0, 0, 0);
                acc[1][nb] = __builtin_amdgcn_mfma_f32_16x16x32_bf16(
                    afr[1][kk], bfr, acc[1][nb], 0, 0, 0);
            }
    }
#pragma unroll
    for (int nb = 0; nb < 8; ++nb) {
        int n = nb * 16 + l16;
        float bv = bias[n];
#pragma unroll
        for (int mb = 0; mb < 2; ++mb)
#pragma unroll
            for (int r = 0; r < 4; ++r) {
                int grow = row0 + w * 32 + mb * 16 + lg * 4 + r;
                if (grow < N) {
                    float v = acc[mb][nb][r] + bv;
                    v = v > 0.f ? v : 0.f;
                    out[(size_t)grow * D + n] = __float2bfloat16(v);
                }
            }
    }
}

// ---------------- fused layer: aggregate->LDS, then K=384 MFMA GEMM ----------
// BM=64 rows/block. Phase 1: 8-lane group per (rel,row) bucket (128 buckets),
// plain broadcast index loads (no shfl -> divergence-safe), fp32 accumulate,
// bf16 store into XOR-swizzled sAgg (32KB). Phase 2: GEMM, A-chunks 1,2 read
// from sAgg via swizzled ds_read_b128; chunk 0 (root) from global hin.
template <bool OUT_F32>
__global__ __launch_bounds__(256)
void k_layer(const __hip_bfloat16* __restrict__ hin,
             const int* __restrict__ srcs,
             const int* __restrict__ off, const int* __restrict__ cnt,
             const float* __restrict__ inv,
             const __hip_bfloat16* __restrict__ Wt,   // [128][384]
             const float* __restrict__ bias,
             void* __restrict__ outv) {
    __shared__ char sAgg[128 * 256];       // 32 KB: bucket bb = rel*64+lr
    __shared__ uint4 sB4[1024];            // 16 KB
    char* sB = (char*)sB4;
    const int tid = threadIdx.x;
    const int row0 = blockIdx.x * 64;

    // ---- phase 1: aggregation ----
    {
        const int grp = tid >> 3, l8 = tid & 7;   // lane covers cols l8*16..+15
        const char* hb = (const char*)hin;
#pragma unroll
        for (int bb = grp; bb < 128; bb += 32) {
            const int rel = bb >> 6, lr = bb & 63;
            const int row = row0 + lr;
            float a[16];
#pragma unroll
            for (int i = 0; i < 16; i++) a[i] = 0.f;
            float sc = 0.f;
            if (row < NN) {
                int wid = rel * NN + row;
                int st = off[wid], c = cnt[wid];
                sc = inv[wid];
                int j = 0;
                for (; j + 1 < c; j += 2) {       // 4 gathers in flight / lane
                    int s0 = srcs[st + j], s1 = srcs[st + j + 1];
                    const char* p0 = hb + (size_t)s0 * 256 + l8 * 32;
                    const char* p1 = hb + (size_t)s1 * 256 + l8 * 32;
                    bf16x8 v0 = *(const bf16x8*)p0;
                    bf16x8 v1 = *(const bf16x8*)(p0 + 16);
                    bf16x8 v2 = *(const bf16x8*)p1;
                    bf16x8 v3 = *(const bf16x8*)(p1 + 16);
#pragma unroll
                    for (int i = 0; i < 8; i++) {
                        a[i]     += bf2f(v0[i]) + bf2f(v2[i]);
                        a[8 + i] += bf2f(v1[i]) + bf2f(v3[i]);
                    }
                }
                if (j < c) {
                    int s0 = srcs[st + j];
                    const char* p0 = hb + (size_t)s0 * 256 + l8 * 32;
                    bf16x8 v0 = *(const bf16x8*)p0;
                    bf16x8 v1 = *(const bf16x8*)(p0 + 16);
#pragma unroll
                    for (int i = 0; i < 8; i++) {
                        a[i]     += bf2f(v0[i]);
                        a[8 + i] += bf2f(v1[i]);
                    }
                }
            }
            float t0[8], t1[8];
#pragma unroll
            for (int i = 0; i < 8; i++) { t0[i] = a[i] * sc; t1[i] = a[8 + i] * sc; }
            const int swz = (bb & 7) << 4;
            char* dstp = sAgg + bb * 256;
            *reinterpret_cast<bf16x8*>(dstp + ((l8 * 32) ^ swz))      = pack_bf8(t0);
            *reinterpret_cast<bf16x8*>(dstp + ((l8 * 32 + 16) ^ swz)) = pack_bf8(t1);
        }
    }

    // ---- phase 2: GEMM over K=384 ----
    const int w = tid >> 6, l16 = tid & 15, lg = (tid & 63) >> 4;
    f32x4 acc[8];
#pragma unroll
    for (int n = 0; n < 8; n++) acc[n] = (f32x4)(0.f);

    const int r_loc = w * 16 + l16;                 // 0..63
#pragma unroll
    for (int kb = 0; kb < 6; ++kb) {
        bf16x8 afr[2];
        if (kb < 2) {
            int r = row0 + r_loc; if (r >= NN) r = NN - 1;
#pragma unroll
            for (int kk = 0; kk < 2; ++kk)
                afr[kk] = *reinterpret_cast<const bf16x8*>(
                    hin + (size_t)r * D + kb * 64 + kk * 32 + lg * 8);
        } else {
            int rel = (kb - 2) >> 1;
            int koff = ((kb - 2) & 1) * 64;
            int bb = rel * 64 + r_loc;
            int swz = (bb & 7) << 4;
#pragma unroll
            for (int kk = 0; kk < 2; ++kk) {
                int bc = (koff + kk * 32 + lg * 8) * 2;
                afr[kk] = *reinterpret_cast<const bf16x8*>(
                    sAgg + bb * 256 + (bc ^ swz));
            }
        }
        __syncthreads();   // protect prev iter's sB reads; kb0 also fences sAgg
        {
            int trow = tid >> 3, tb = (tid & 7) * 16;
#pragma unroll
            for (int p = 0; p < 4; ++p) {
                int rr = trow + p * 32;
                uint4 v = *reinterpret_cast<const uint4*>(
                    (const char*)(Wt + (size_t)rr * 384 + kb * 64) + tb);
                *reinterpret_cast<uint4*>(sB + rr * 128 + (tb ^ ((rr & 7) << 4))) = v;
            }
        }
        __syncthreads();
#pragma unroll
        for (int kk = 0; kk < 2; ++kk)
#pragma unroll
            for (int nb = 0; nb < 8; ++nb) {
                int brow = nb * 16 + l16;
                int bcol = kk * 64 + lg * 16;
                bf16x8 bfr = *reinterpret_cast<const bf16x8*>(
                    sB + brow * 128 + (bcol ^ ((brow & 7) << 4)));
                acc[nb] = __builtin_amdgcn_mfma_f32_16x16x32_bf16(
                    afr[kk], bfr, acc[nb], 0, 0, 0);
            }
    }
    // epilogue: row = row0 + w*16 + lg*4 + r, col = nb*16 + l16
#pragma unroll
    for (int nb = 0; nb < 8; ++nb) {
        int n = nb * 16 + l16;
        float bv = bias[n];
#pragma unroll
        for (int r = 0; r < 4; ++r) {
            int grow = row0 + w * 16 + lg * 4 + r;
            if (grow < NN) {
                float v = acc[nb][r] + bv;
                v = v > 0.f ? v : 0.f;
                if (OUT_F32)
                    ((float*)outv)[(size_t)grow * D + n] = v;
                else
                    ((__hip_bfloat16*)outv)[(size_t)grow * D + n] =
                        __float2bfloat16(v);
            }
        }
    }
}

extern "C" void kernel_launch(void* const* d_in, const int* in_sizes, int n_in,
                              void* d_out, int out_size, void* d_ws, size_t ws_size,
                              hipStream_t stream) {
    const float* x    = (const float*)d_in[0];
    const int*   ei   = (const int*)d_in[1];
    const float* attr = (const float*)d_in[2];
    const float* Wf   = (const float*)d_in[3];
    const float* bf   = (const float*)d_in[4];
    const float* cw   = (const float*)d_in[5];  // [3][2][128][128]
    const float* cr   = (const float*)d_in[6];  // [3][128][128]
    const float* cb   = (const float*)d_in[7];  // [3][128]
    const int* src  = ei;
    const int* dstv = ei + NE;

    // workspace layout (bytes)
    char* p = (char*)d_ws;
    __hip_bfloat16* h0 = (__hip_bfloat16*)p; p += (size_t)NN * D * 2;
    __hip_bfloat16* h1 = (__hip_bfloat16*)p; p += (size_t)NN * D * 2;
    __hip_bfloat16* wt = (__hip_bfloat16*)p; p += (size_t)(16384 + 3 * 49152) * 2;
    float* inv  = (float*)p;                p += (size_t)2 * NN * 4;
    int*   cnt  = (int*)p;                  p += (size_t)2 * NN * 4;
    int*   off  = (int*)p;                  p += (size_t)2 * NN * 4;
    int*   cur  = (int*)p;                  p += (size_t)2 * NN * 4;
    int*   srcs = (int*)p;                  p += (size_t)NE * 4;
    int*   total= (int*)p;

    float* outp = (float*)d_out;

    // ---- layer-invariant preprocessing ----
    hipMemsetAsync(cnt, 0, (size_t)2 * NN * sizeof(int), stream);
    hipMemsetAsync(total, 0, sizeof(int), stream);
    k_count<<<(NE + 255) / 256, 256, 0, stream>>>(attr, dstv, cnt, NE);
    k_inv<<<(2 * NN + 255) / 256, 256, 0, stream>>>(cnt, inv);
    k_alloc<<<(2 * NN + 255) / 256, 256, 0, stream>>>(cnt, off, cur, total);
    k_fill<<<(NE + 255) / 256, 256, 0, stream>>>(attr, src, dstv, cur, srcs, NE);
    k_prep_w<<<(16384 + 3 * 49152 + 255) / 256, 256, 0, stream>>>(Wf, cw, cr, wt);

    // input projection (f32 x read directly)
    k_gemm_proj<<<(NN + 127) / 128, 256, 0, stream>>>(x, wt, bf, h0, NN);

    const int lblocks = (NN + 63) / 64;
    for (int l = 0; l < 3; ++l) {
        const __hip_bfloat16* hin = (l == 1) ? h1 : h0;
        const __hip_bfloat16* wl = wt + 16384 + (size_t)l * 49152;
        const float* bl = cb + (size_t)l * D;
        if (l == 2) {
            k_layer<true><<<lblocks, 256, 0, stream>>>(
                hin, srcs, off, cnt, inv, wl, bl, outp);
        } else {
            __hip_bfloat16* hout = (l == 0) ? h1 : h0;
            k_layer<false><<<lblocks, 256, 0, stream>>>(
                hin, srcs, off, cnt, inv, wl, bl, hout);
        }
    }
}

// Round 8
// 271.096 us; speedup vs baseline: 1.0676x; 1.0676x over previous
//
#include <hip/hip_runtime.h>
#include <hip/hip_bf16.h>

#define NN 50000
#define NE 600000
#define D 128
#define NREL 2
#define BM 128

typedef __attribute__((ext_vector_type(8))) short bf16x8;   // 8 bf16 (4 VGPRs)
typedef __attribute__((ext_vector_type(4))) float f32x4;    // 4 fp32 acc

__device__ __forceinline__ float bf2f(short s) {
    return __uint_as_float(((unsigned int)(unsigned short)s) << 16);
}
__device__ __forceinline__ bf16x8 pack_bf8(const float* a) {
    union { bf16x8 v; __hip_bfloat162 h2[4]; } o;
#pragma unroll
    for (int i = 0; i < 4; i++)
        o.h2[i] = __float22bfloat162_rn(make_float2(a[2 * i], a[2 * i + 1]));
    return o.v;
}

#define NEB ((NE + 255) / 256)          // edge blocks
#define NWT (16384 + 3 * 49152)         // wt elements
#define NWB ((NWT + 255) / 256)         // prep_w blocks

// ---------------- fused: edge count (blocks < NEB) + weight prep (rest) ------
// wt[0:16384)                  : proj  Wtp[n][k] = Wf[k][n]          (K=128)
// wt[16384 + l*49152 + n*384+k]: layer l, k<128 root, <256 W0, else W1
__global__ void k_pre1(const float* __restrict__ attr,
                       const int* __restrict__ dst,
                       int* __restrict__ cnt,
                       const float* __restrict__ Wf,
                       const float* __restrict__ cw,
                       const float* __restrict__ cr,
                       __hip_bfloat16* __restrict__ wt) {
    if (blockIdx.x < NEB) {
        int i = blockIdx.x * blockDim.x + threadIdx.x;
        if (i >= NE) return;
        float2 a = reinterpret_cast<const float2*>(attr)[i];
        int r = (a.y > a.x) ? 1 : 0;   // argmax, first-index tiebreak
        atomicAdd(&cnt[r * NN + dst[i]], 1);
    } else {
        int idx = (blockIdx.x - NEB) * blockDim.x + threadIdx.x;
        if (idx >= NWT) return;
        float v;
        if (idx < 16384) {
            int n = idx >> 7, k = idx & 127;
            v = Wf[k * 128 + n];
        } else {
            int j = idx - 16384;
            int l = j / 49152; j %= 49152;
            int n = j / 384, k = j % 384;
            if (k < 128)      v = cr[((size_t)l * 128 + k) * 128 + n];
            else if (k < 256) v = cw[((size_t)(l * 2 + 0) * 128 + (k - 128)) * 128 + n];
            else              v = cw[((size_t)(l * 2 + 1) * 128 + (k - 256)) * 128 + n];
        }
        wt[idx] = __float2bfloat16(v);
    }
}

// ---------------- inv + bucket allocator in one pass over 100k ---------------
__global__ void k_pre2(const int* __restrict__ cnt, float* __restrict__ inv,
                       int* __restrict__ off, int* __restrict__ cur,
                       int* __restrict__ total) {
    int i = blockIdx.x * blockDim.x + threadIdx.x;
    if (i >= NREL * NN) return;
    int c = cnt[i];
    inv[i] = 1.0f / (float)(c > 1 ? c : 1);
    int o = atomicAdd(total, c);         // wave-coalesced by atomic optimizer
    off[i] = o;
    cur[i] = o;
}

// ---------------- fill CSR: srcs[pos] = src[e], bucketed by (rel,dst) --------
__global__ void k_fill(const float* __restrict__ attr,
                       const int* __restrict__ src, const int* __restrict__ dst,
                       int* __restrict__ cursor, int* __restrict__ srcs, int E) {
    int i = blockIdx.x * blockDim.x + threadIdx.x;
    if (i >= E) return;
    float2 a = reinterpret_cast<const float2*>(attr)[i];
    int r = (a.y > a.x) ? 1 : 0;
    int pos = atomicAdd(&cursor[r * NN + dst[i]], 1);
    srcs[pos] = src[i];
}

// ---------------- aggregation: one wave per (rel,node) bucket ----------------
// 4 x 16-lane groups; lane loads 16B (bf16x8); group g handles edges
// base+g, +4, +8, +12 -> 16 unconditional gathers in flight per wave.
// Loop bound is wave-uniform (c shared by whole wave) so every __shfl runs
// with all 64 lanes active (R5 lesson: divergent shfl = garbage on CDNA).
// OOB edges load row 0 (valid, cache-hot) and are masked at the accumulate.
__global__ __launch_bounds__(256)
void k_aggregate(const __hip_bfloat16* __restrict__ h,
                 const int* __restrict__ srcs,
                 const int* __restrict__ off, const int* __restrict__ cnt,
                 const float* __restrict__ inv,
                 __hip_bfloat16* __restrict__ agg) {
    int wid = (blockIdx.x * blockDim.x + threadIdx.x) >> 6;
    int lane = threadIdx.x & 63;
    if (wid >= NREL * NN) return;
    int start = off[wid], c = cnt[wid];
    int g = lane >> 4, l16 = lane & 15;

    int sv = (lane < c) ? srcs[start + lane] : 0;   // one coalesced index load

    float acc[8];
#pragma unroll
    for (int i = 0; i < 8; i++) acc[i] = 0.f;

    for (int base = 0; base < c; base += 16) {      // wave-uniform trip count
        int s[4];
#pragma unroll
        for (int q = 0; q < 4; q++) {
            int jj = base + g + q * 4;
            int t = __shfl(sv, jj & 63);            // full-exec shfl
            s[q] = (jj < 64) ? t : ((jj < c) ? srcs[start + jj] : 0);
            if (jj >= c) s[q] = 0;                  // clamp: row 0 always valid
        }
        bf16x8 v[4];
#pragma unroll
        for (int q = 0; q < 4; q++)                 // 4 independent loads issued
            v[q] = *reinterpret_cast<const bf16x8*>(h + (size_t)s[q] * D + l16 * 8);
#pragma unroll
        for (int q = 0; q < 4; q++) {
            bool ok = (base + g + q * 4) < c;
#pragma unroll
            for (int i = 0; i < 8; i++) acc[i] += ok ? bf2f(v[q][i]) : 0.f;
        }
    }

    // reduce across the 4 groups (lanes l16, l16+16, l16+32, l16+48)
#pragma unroll
    for (int i = 0; i < 8; i++) acc[i] += __shfl_xor(acc[i], 16);
#pragma unroll
    for (int i = 0; i < 8; i++) acc[i] += __shfl_xor(acc[i], 32);

    if (g == 0) {
        float sc = inv[wid];
        float t[8];
#pragma unroll
        for (int i = 0; i < 8; i++) t[i] = acc[i] * sc;
        *reinterpret_cast<bf16x8*>(agg + (size_t)wid * D + l16 * 8) = pack_bf8(t);
    }
}

// ---------------- proj GEMM: h0 = relu(x_f32 @ Wtp^T + bf), bf16 out ---------
__global__ __launch_bounds__(256)
void k_gemm_proj(const float* __restrict__ X,
                 const __hip_bfloat16* __restrict__ Wt,   // [128][128]
                 const float* __restrict__ bias,
                 __hip_bfloat16* __restrict__ out, int N) {
    __shared__ uint4 sB4[1024];            // 16 KB
    char* sB = (char*)sB4;
    const int tid = threadIdx.x;
    const int w = tid >> 6;
    const int l16 = tid & 15, lg = (tid & 63) >> 4;

    f32x4 acc[2][8];
#pragma unroll
    for (int m = 0; m < 2; m++)
#pragma unroll
        for (int n = 0; n < 8; n++) acc[m][n] = (f32x4)(0.f);

    const int row0 = blockIdx.x * 128;
#pragma unroll
    for (int kb = 0; kb < 2; ++kb) {
        bf16x8 afr[2][2];
#pragma unroll
        for (int mb = 0; mb < 2; ++mb)
#pragma unroll
            for (int kk = 0; kk < 2; ++kk) {
                int r = row0 + w * 32 + mb * 16 + l16;
                if (r >= N) r = N - 1;
                const float* p = X + (size_t)r * D + kb * 64 + kk * 32 + lg * 8;
                float4 u0 = reinterpret_cast<const float4*>(p)[0];
                float4 u1 = reinterpret_cast<const float4*>(p)[1];
                float t[8] = {u0.x, u0.y, u0.z, u0.w, u1.x, u1.y, u1.z, u1.w};
                afr[mb][kk] = pack_bf8(t);
            }
        __syncthreads();
        {
            int trow = tid >> 3, tb = (tid & 7) * 16;
#pragma unroll
            for (int p = 0; p < 4; ++p) {
                int rr = trow + p * 32;
                uint4 v = *reinterpret_cast<const uint4*>(
                    (const char*)(Wt + (size_t)rr * 128 + kb * 64) + tb);
                *reinterpret_cast<uint4*>(sB + rr * 128 + (tb ^ ((rr & 7) << 4))) = v;
            }
        }
        __syncthreads();
#pragma unroll
        for (int kk = 0; kk < 2; ++kk)
#pragma unroll
            for (int nb = 0; nb < 8; ++nb) {
                int brow = nb * 16 + l16;
                int bcol = kk * 64 + lg * 16;
                bf16x8 bfr = *reinterpret_cast<const bf16x8*>(
                    sB + brow * 128 + (bcol ^ ((brow & 7) << 4)));
                acc[0][nb] = __builtin_amdgcn_mfma_f32_16x16x32_bf16(
                    afr[0][kk], bfr, acc[0][nb], 0, 0, 0);
                acc[1][nb] = __builtin_amdgcn_mfma_f32_16x16x32_bf16(
                    afr[1][kk], bfr, acc[1][nb], 0, 0, 0);
            }
    }
#pragma unroll
    for (int nb = 0; nb < 8; ++nb) {
        int n = nb * 16 + l16;
        float bv = bias[n];
#pragma unroll
        for (int mb = 0; mb < 2; ++mb)
#pragma unroll
            for (int r = 0; r < 4; ++r) {
                int grow = row0 + w * 32 + mb * 16 + lg * 4 + r;
                if (grow < N) {
                    float v = acc[mb][nb][r] + bv;
                    v = v > 0.f ? v : 0.f;
                    out[(size_t)grow * D + n] = __float2bfloat16(v);
                }
            }
    }
}

// ---------------- MFMA GEMM: out = relu([A0|A1|A2] @ Wt^T + bias) ------------
template <int KTOT, bool OUT_F32>
__global__ __launch_bounds__(256)
void k_gemm_mfma(const __hip_bfloat16* __restrict__ A0,
                 const __hip_bfloat16* __restrict__ A1,
                 const __hip_bfloat16* __restrict__ A2,
                 const __hip_bfloat16* __restrict__ Wt,   // [128][KTOT]
                 const float* __restrict__ bias,
                 void* __restrict__ outv, int N) {
    __shared__ uint4 sB4[1024];            // 16 KB
    char* sB = (char*)sB4;
    const int tid = threadIdx.x;
    const int w = tid >> 6;
    const int l16 = tid & 15, lg = (tid & 63) >> 4;
    const __hip_bfloat16* As[3] = {A0, A1, A2};

    f32x4 acc[2][8];
#pragma unroll
    for (int m = 0; m < 2; m++)
#pragma unroll
        for (int n = 0; n < 8; n++) acc[m][n] = (f32x4)(0.f);

    const size_t row0 = (size_t)blockIdx.x * BM;
    const int NKB = KTOT / 64;
#pragma unroll
    for (int kb = 0; kb < NKB; ++kb) {
        const __hip_bfloat16* Ac = As[kb >> 1];
        const int koff = (kb & 1) * 64;
        bf16x8 afr[2][2];
#pragma unroll
        for (int mb = 0; mb < 2; ++mb)
#pragma unroll
            for (int kk = 0; kk < 2; ++kk) {
                int r = (int)row0 + w * 32 + mb * 16 + l16;
                if (r >= N) r = N - 1;              // clamped; store-guarded later
                afr[mb][kk] = *reinterpret_cast<const bf16x8*>(
                    Ac + (size_t)r * D + koff + kk * 32 + lg * 8);
            }
        __syncthreads();   // previous kb's sB reads complete
        {
            int trow = tid >> 3;
            int tb = (tid & 7) * 16;               // byte col within 128B row
#pragma unroll
            for (int p = 0; p < 4; ++p) {
                int rr = trow + p * 32;
                uint4 v = *reinterpret_cast<const uint4*>(
                    (const char*)(Wt + (size_t)rr * KTOT + kb * 64) + tb);
                *reinterpret_cast<uint4*>(sB + rr * 128 + (tb ^ ((rr & 7) << 4))) = v;
            }
        }
        __syncthreads();
#pragma unroll
        for (int kk = 0; kk < 2; ++kk) {
#pragma unroll
            for (int nb = 0; nb < 8; ++nb) {
                int brow = nb * 16 + l16;
                int bcol = kk * 64 + lg * 16;
                bf16x8 bfr = *reinterpret_cast<const bf16x8*>(
                    sB + brow * 128 + (bcol ^ ((brow & 7) << 4)));
                acc[0][nb] = __builtin_amdgcn_mfma_f32_16x16x32_bf16(
                    afr[0][kk], bfr, acc[0][nb], 0, 0, 0);
                acc[1][nb] = __builtin_amdgcn_mfma_f32_16x16x32_bf16(
                    afr[1][kk], bfr, acc[1][nb], 0, 0, 0);
            }
        }
    }
#pragma unroll
    for (int nb = 0; nb < 8; ++nb) {
        int n = nb * 16 + l16;
        float bv = bias[n];
#pragma unroll
        for (int mb = 0; mb < 2; ++mb) {
#pragma unroll
            for (int r = 0; r < 4; ++r) {
                long grow = (long)row0 + w * 32 + mb * 16 + lg * 4 + r;
                if (grow < N) {
                    float v = acc[mb][nb][r] + bv;
                    v = v > 0.f ? v : 0.f;
                    if (OUT_F32)
                        ((float*)outv)[(size_t)grow * D + n] = v;
                    else
                        ((__hip_bfloat16*)outv)[(size_t)grow * D + n] =
                            __float2bfloat16(v);
                }
            }
        }
    }
}

extern "C" void kernel_launch(void* const* d_in, const int* in_sizes, int n_in,
                              void* d_out, int out_size, void* d_ws, size_t ws_size,
                              hipStream_t stream) {
    const float* x    = (const float*)d_in[0];
    const int*   ei   = (const int*)d_in[1];
    const float* attr = (const float*)d_in[2];
    const float* Wf   = (const float*)d_in[3];
    const float* bf   = (const float*)d_in[4];
    const float* cw   = (const float*)d_in[5];  // [3][2][128][128]
    const float* cr   = (const float*)d_in[6];  // [3][128][128]
    const float* cb   = (const float*)d_in[7];  // [3][128]
    const int* src  = ei;
    const int* dstv = ei + NE;

    // workspace layout (bytes)
    char* p = (char*)d_ws;
    __hip_bfloat16* h0   = (__hip_bfloat16*)p; p += (size_t)NN * D * 2;
    __hip_bfloat16* h1   = (__hip_bfloat16*)p; p += (size_t)NN * D * 2;
    __hip_bfloat16* aggb = (__hip_bfloat16*)p; p += (size_t)2 * NN * D * 2;
    __hip_bfloat16* wt   = (__hip_bfloat16*)p; p += (size_t)NWT * 2;
    float* inv  = (float*)p;                p += (size_t)2 * NN * 4;
    int*   cnt  = (int*)p;                  p += (size_t)2 * NN * 4;
    int*   off  = (int*)p;                  p += (size_t)2 * NN * 4;
    int*   cur  = (int*)p;                  p += (size_t)2 * NN * 4;
    int*   srcs = (int*)p;                  p += (size_t)NE * 4;
    int*   total= (int*)p;

    float* outp = (float*)d_out;

    // ---- layer-invariant preprocessing (9 dispatches total in graph) ----
    hipMemsetAsync(cnt, 0, (size_t)2 * NN * sizeof(int), stream);
    hipMemsetAsync(total, 0, sizeof(int), stream);
    k_pre1<<<NEB + NWB, 256, 0, stream>>>(attr, dstv, cnt, Wf, cw, cr, wt);
    k_pre2<<<(2 * NN + 255) / 256, 256, 0, stream>>>(cnt, inv, off, cur, total);
    k_fill<<<NEB, 256, 0, stream>>>(attr, src, dstv, cur, srcs, NE);

    // input projection (f32 x read directly)
    k_gemm_proj<<<(NN + 127) / 128, 256, 0, stream>>>(x, wt, bf, h0, NN);

    const int gblocks = (NN + BM - 1) / BM;
    const int ablocks = (2 * NN * 64 + 255) / 256;  // one wave per (rel,node)
    for (int l = 0; l < 3; ++l) {
        const __hip_bfloat16* hin = (l == 1) ? h1 : h0;
        k_aggregate<<<ablocks, 256, 0, stream>>>(hin, srcs, off, cnt, inv, aggb);
        const __hip_bfloat16* wl = wt + 16384 + (size_t)l * 49152;
        const float* bl = cb + (size_t)l * D;
        if (l == 2) {
            k_gemm_mfma<384, true><<<gblocks, 256, 0, stream>>>(
                hin, aggb, aggb + (size_t)NN * D, wl, bl, outp, NN);
        } else {
            __hip_bfloat16* hout = (l == 0) ? h1 : h0;
            k_gemm_mfma<384, false><<<gblocks, 256, 0, stream>>>(
                hin, aggb, aggb + (size_t)NN * D, wl, bl, hout, NN);
        }
    }
}

// Round 9
// 269.116 us; speedup vs baseline: 1.0755x; 1.0074x over previous
//
#include <hip/hip_runtime.h>
#include <hip/hip_bf16.h>

#define NN 50000
#define NE 600000
#define D 128
#define NREL 2
#define BM 128

typedef __attribute__((ext_vector_type(8))) short bf16x8;   // 8 bf16 (4 VGPRs)
typedef __attribute__((ext_vector_type(4))) float f32x4;    // 4 fp32 acc

__device__ __forceinline__ float bf2f(short s) {
    return __uint_as_float(((unsigned int)(unsigned short)s) << 16);
}
__device__ __forceinline__ bf16x8 pack_bf8(const float* a) {
    union { bf16x8 v; __hip_bfloat162 h2[4]; } o;
#pragma unroll
    for (int i = 0; i < 4; i++)
        o.h2[i] = __float22bfloat162_rn(make_float2(a[2 * i], a[2 * i + 1]));
    return o.v;
}

#define NEB ((NE + 255) / 256)          // edge blocks
#define NWT (16384 + 3 * 49152)         // wt elements
#define NWB ((NWT + 255) / 256)         // prep_w blocks

// ---------------- fused: edge count (blocks < NEB) + weight prep (rest) ------
// bucket key = dst*2 + rel (node-major, rel minor)
// wt[0:16384)                  : proj  Wtp[n][k] = Wf[k][n]          (K=128)
// wt[16384 + l*49152 + n*384+k]: layer l, k<128 root, <256 W0, else W1
__global__ void k_pre1(const float* __restrict__ attr,
                       const int* __restrict__ dst,
                       int* __restrict__ cnt,
                       const float* __restrict__ Wf,
                       const float* __restrict__ cw,
                       const float* __restrict__ cr,
                       __hip_bfloat16* __restrict__ wt) {
    if (blockIdx.x < NEB) {
        int i = blockIdx.x * blockDim.x + threadIdx.x;
        if (i >= NE) return;
        float2 a = reinterpret_cast<const float2*>(attr)[i];
        int r = (a.y > a.x) ? 1 : 0;   // argmax, first-index tiebreak
        atomicAdd(&cnt[dst[i] * 2 + r], 1);
    } else {
        int idx = (blockIdx.x - NEB) * blockDim.x + threadIdx.x;
        if (idx >= NWT) return;
        float v;
        if (idx < 16384) {
            int n = idx >> 7, k = idx & 127;
            v = Wf[k * 128 + n];
        } else {
            int j = idx - 16384;
            int l = j / 49152; j %= 49152;
            int n = j / 384, k = j % 384;
            if (k < 128)      v = cr[((size_t)l * 128 + k) * 128 + n];
            else if (k < 256) v = cw[((size_t)(l * 2 + 0) * 128 + (k - 128)) * 128 + n];
            else              v = cw[((size_t)(l * 2 + 1) * 128 + (k - 256)) * 128 + n];
        }
        wt[idx] = __float2bfloat16(v);
    }
}

// ---------------- inv + per-NODE bucket allocator ----------------------------
// One thread per node: allocates c0+c1 contiguous slots; bucket 2n at o,
// bucket 2n+1 at o+c0. So each node's two relation buckets are adjacent.
__global__ void k_pre2(const int* __restrict__ cnt, float* __restrict__ inv,
                       int* __restrict__ off, int* __restrict__ cur,
                       int* __restrict__ total) {
    int i = blockIdx.x * blockDim.x + threadIdx.x;
    if (i >= NN) return;
    int c0 = cnt[2 * i], c1 = cnt[2 * i + 1];
    inv[2 * i]     = 1.0f / (float)(c0 > 1 ? c0 : 1);
    inv[2 * i + 1] = 1.0f / (float)(c1 > 1 ? c1 : 1);
    int o = atomicAdd(total, c0 + c1);   // wave-coalesced by atomic optimizer
    off[2 * i] = o;       cur[2 * i] = o;
    off[2 * i + 1] = o + c0; cur[2 * i + 1] = o + c0;
}

// ---------------- fill CSR: srcs[pos] = src[e], bucketed by (dst,rel) --------
__global__ void k_fill(const float* __restrict__ attr,
                       const int* __restrict__ src, const int* __restrict__ dst,
                       int* __restrict__ cursor, int* __restrict__ srcs, int E) {
    int i = blockIdx.x * blockDim.x + threadIdx.x;
    if (i >= E) return;
    float2 a = reinterpret_cast<const float2*>(attr)[i];
    int r = (a.y > a.x) ? 1 : 0;
    int pos = atomicAdd(&cursor[dst[i] * 2 + r], 1);
    srcs[pos] = src[i];
}

// ---------------- aggregation: one wave per NODE (both relations) ------------
// Node's two buckets are contiguous: edges [st, st+c0) are rel0, [st+c0, st+c01)
// are rel1. 4 x 16-lane groups, 4-deep unconditional gathers (16 in flight),
// masked dual accumulation. All __shfl at full exec (wave-uniform loop bound;
// R5 lesson). Output layout agg[node][rel][128] -> one 512B store per node.
__global__ __launch_bounds__(256)
void k_aggregate(const __hip_bfloat16* __restrict__ h,
                 const int* __restrict__ srcs,
                 const int* __restrict__ off, const int* __restrict__ cnt,
                 const float* __restrict__ inv,
                 __hip_bfloat16* __restrict__ agg) {
    int node = (blockIdx.x * blockDim.x + threadIdx.x) >> 6;
    int lane = threadIdx.x & 63;
    if (node >= NN) return;
    int st = off[2 * node];
    int c0 = cnt[2 * node], c01 = c0 + cnt[2 * node + 1];
    int g = lane >> 4, l16 = lane & 15;

    int sv = (lane < c01) ? srcs[st + lane] : 0;    // one coalesced index load

    float acc0[8], acc1[8];
#pragma unroll
    for (int i = 0; i < 8; i++) { acc0[i] = 0.f; acc1[i] = 0.f; }

    if (c01 <= 64) {                                 // fast path (typical)
        for (int base = 0; base < c01; base += 16) { // wave-uniform trip count
            int s[4]; int jj[4];
#pragma unroll
            for (int q = 0; q < 4; q++) {
                jj[q] = base + g + q * 4;
                int t = __shfl(sv, jj[q] & 63);      // full-exec shfl
                s[q] = (jj[q] < c01) ? t : 0;        // clamp: row 0 valid
            }
            bf16x8 v[4];
#pragma unroll
            for (int q = 0; q < 4; q++)              // 4 independent loads
                v[q] = *reinterpret_cast<const bf16x8*>(
                    h + (size_t)s[q] * D + l16 * 8);
#pragma unroll
            for (int q = 0; q < 4; q++) {
                bool ok0 = jj[q] < c0;
                bool ok1 = !ok0 && (jj[q] < c01);
#pragma unroll
                for (int i = 0; i < 8; i++) {
                    float f = bf2f(v[q][i]);
                    acc0[i] += ok0 ? f : 0.f;
                    acc1[i] += ok1 ? f : 0.f;
                }
            }
        }
    } else {                                         // rare hub-node path
        for (int base = 0; base < c01; base += 16) {
            int s[4]; int jj[4];
#pragma unroll
            for (int q = 0; q < 4; q++) {
                jj[q] = base + g + q * 4;
                int t = __shfl(sv, jj[q] & 63);
                s[q] = (jj[q] < 64) ? t : ((jj[q] < c01) ? srcs[st + jj[q]] : 0);
                if (jj[q] >= c01) s[q] = 0;
            }
            bf16x8 v[4];
#pragma unroll
            for (int q = 0; q < 4; q++)
                v[q] = *reinterpret_cast<const bf16x8*>(
                    h + (size_t)s[q] * D + l16 * 8);
#pragma unroll
            for (int q = 0; q < 4; q++) {
                bool ok0 = jj[q] < c0;
                bool ok1 = !ok0 && (jj[q] < c01);
#pragma unroll
                for (int i = 0; i < 8; i++) {
                    float f = bf2f(v[q][i]);
                    acc0[i] += ok0 ? f : 0.f;
                    acc1[i] += ok1 ? f : 0.f;
                }
            }
        }
    }

    // reduce across the 4 groups (lanes l16, l16+16, l16+32, l16+48)
#pragma unroll
    for (int i = 0; i < 8; i++) {
        acc0[i] += __shfl_xor(acc0[i], 16);
        acc1[i] += __shfl_xor(acc1[i], 16);
    }
#pragma unroll
    for (int i = 0; i < 8; i++) {
        acc0[i] += __shfl_xor(acc0[i], 32);
        acc1[i] += __shfl_xor(acc1[i], 32);
    }

    if (g == 0) {
        float s0 = inv[2 * node], s1 = inv[2 * node + 1];
        float t0[8], t1[8];
#pragma unroll
        for (int i = 0; i < 8; i++) { t0[i] = acc0[i] * s0; t1[i] = acc1[i] * s1; }
        __hip_bfloat16* dstp = agg + (size_t)node * 256;
        *reinterpret_cast<bf16x8*>(dstp + l16 * 8)       = pack_bf8(t0);
        *reinterpret_cast<bf16x8*>(dstp + 128 + l16 * 8) = pack_bf8(t1);
    }
}

// ---------------- proj GEMM: h0 = relu(x_f32 @ Wtp^T + bf), bf16 out ---------
__global__ __launch_bounds__(256)
void k_gemm_proj(const float* __restrict__ X,
                 const __hip_bfloat16* __restrict__ Wt,   // [128][128]
                 const float* __restrict__ bias,
                 __hip_bfloat16* __restrict__ out, int N) {
    __shared__ uint4 sB4[1024];            // 16 KB
    char* sB = (char*)sB4;
    const int tid = threadIdx.x;
    const int w = tid >> 6;
    const int l16 = tid & 15, lg = (tid & 63) >> 4;

    f32x4 acc[2][8];
#pragma unroll
    for (int m = 0; m < 2; m++)
#pragma unroll
        for (int n = 0; n < 8; n++) acc[m][n] = (f32x4)(0.f);

    const int row0 = blockIdx.x * 128;
#pragma unroll
    for (int kb = 0; kb < 2; ++kb) {
        bf16x8 afr[2][2];
#pragma unroll
        for (int mb = 0; mb < 2; ++mb)
#pragma unroll
            for (int kk = 0; kk < 2; ++kk) {
                int r = row0 + w * 32 + mb * 16 + l16;
                if (r >= N) r = N - 1;
                const float* p = X + (size_t)r * D + kb * 64 + kk * 32 + lg * 8;
                float4 u0 = reinterpret_cast<const float4*>(p)[0];
                float4 u1 = reinterpret_cast<const float4*>(p)[1];
                float t[8] = {u0.x, u0.y, u0.z, u0.w, u1.x, u1.y, u1.z, u1.w};
                afr[mb][kk] = pack_bf8(t);
            }
        __syncthreads();
        {
            int trow = tid >> 3, tb = (tid & 7) * 16;
#pragma unroll
            for (int p = 0; p < 4; ++p) {
                int rr = trow + p * 32;
                uint4 v = *reinterpret_cast<const uint4*>(
                    (const char*)(Wt + (size_t)rr * 128 + kb * 64) + tb);
                *reinterpret_cast<uint4*>(sB + rr * 128 + (tb ^ ((rr & 7) << 4))) = v;
            }
        }
        __syncthreads();
#pragma unroll
        for (int kk = 0; kk < 2; ++kk)
#pragma unroll
            for (int nb = 0; nb < 8; ++nb) {
                int brow = nb * 16 + l16;
                int bcol = kk * 64 + lg * 16;
                bf16x8 bfr = *reinterpret_cast<const bf16x8*>(
                    sB + brow * 128 + (bcol ^ ((brow & 7) << 4)));
                acc[0][nb] = __builtin_amdgcn_mfma_f32_16x16x32_bf16(
                    afr[0][kk], bfr, acc[0][nb], 0, 0, 0);
                acc[1][nb] = __builtin_amdgcn_mfma_f32_16x16x32_bf16(
                    afr[1][kk], bfr, acc[1][nb], 0, 0, 0);
            }
    }
#pragma unroll
    for (int nb = 0; nb < 8; ++nb) {
        int n = nb * 16 + l16;
        float bv = bias[n];
#pragma unroll
        for (int mb = 0; mb < 2; ++mb)
#pragma unroll
            for (int r = 0; r < 4; ++r) {
                int grow = row0 + w * 32 + mb * 16 + lg * 4 + r;
                if (grow < N) {
                    float v = acc[mb][nb][r] + bv;
                    v = v > 0.f ? v : 0.f;
                    out[(size_t)grow * D + n] = __float2bfloat16(v);
                }
            }
    }
}

// ---------------- MFMA GEMM: out = relu([A0|A1|A2] @ Wt^T + bias) ------------
// Per-chunk row stride (elements): hin is 128, agg (interleaved) is 256.
template <bool OUT_F32>
__global__ __launch_bounds__(256)
void k_gemm_mfma(const __hip_bfloat16* __restrict__ A0, int sA0,
                 const __hip_bfloat16* __restrict__ A1, int sA1,
                 const __hip_bfloat16* __restrict__ A2, int sA2,
                 const __hip_bfloat16* __restrict__ Wt,   // [128][384]
                 const float* __restrict__ bias,
                 void* __restrict__ outv, int N) {
    __shared__ uint4 sB4[1024];            // 16 KB
    char* sB = (char*)sB4;
    const int tid = threadIdx.x;
    const int w = tid >> 6;
    const int l16 = tid & 15, lg = (tid & 63) >> 4;
    const __hip_bfloat16* As[3] = {A0, A1, A2};
    const int strides[3] = {sA0, sA1, sA2};

    f32x4 acc[2][8];
#pragma unroll
    for (int m = 0; m < 2; m++)
#pragma unroll
        for (int n = 0; n < 8; n++) acc[m][n] = (f32x4)(0.f);

    const size_t row0 = (size_t)blockIdx.x * BM;
#pragma unroll
    for (int kb = 0; kb < 6; ++kb) {
        const __hip_bfloat16* Ac = As[kb >> 1];
        const int strideC = strides[kb >> 1];
        const int koff = (kb & 1) * 64;
        bf16x8 afr[2][2];
#pragma unroll
        for (int mb = 0; mb < 2; ++mb)
#pragma unroll
            for (int kk = 0; kk < 2; ++kk) {
                int r = (int)row0 + w * 32 + mb * 16 + l16;
                if (r >= N) r = N - 1;              // clamped; store-guarded later
                afr[mb][kk] = *reinterpret_cast<const bf16x8*>(
                    Ac + (size_t)r * strideC + koff + kk * 32 + lg * 8);
            }
        __syncthreads();   // previous kb's sB reads complete
        {
            int trow = tid >> 3;
            int tb = (tid & 7) * 16;               // byte col within 128B row
#pragma unroll
            for (int p = 0; p < 4; ++p) {
                int rr = trow + p * 32;
                uint4 v = *reinterpret_cast<const uint4*>(
                    (const char*)(Wt + (size_t)rr * 384 + kb * 64) + tb);
                *reinterpret_cast<uint4*>(sB + rr * 128 + (tb ^ ((rr & 7) << 4))) = v;
            }
        }
        __syncthreads();
#pragma unroll
        for (int kk = 0; kk < 2; ++kk) {
#pragma unroll
            for (int nb = 0; nb < 8; ++nb) {
                int brow = nb * 16 + l16;
                int bcol = kk * 64 + lg * 16;
                bf16x8 bfr = *reinterpret_cast<const bf16x8*>(
                    sB + brow * 128 + (bcol ^ ((brow & 7) << 4)));
                acc[0][nb] = __builtin_amdgcn_mfma_f32_16x16x32_bf16(
                    afr[0][kk], bfr, acc[0][nb], 0, 0, 0);
                acc[1][nb] = __builtin_amdgcn_mfma_f32_16x16x32_bf16(
                    afr[1][kk], bfr, acc[1][nb], 0, 0, 0);
            }
        }
    }
#pragma unroll
    for (int nb = 0; nb < 8; ++nb) {
        int n = nb * 16 + l16;
        float bv = bias[n];
#pragma unroll
        for (int mb = 0; mb < 2; ++mb) {
#pragma unroll
            for (int r = 0; r < 4; ++r) {
                long grow = (long)row0 + w * 32 + mb * 16 + lg * 4 + r;
                if (grow < N) {
                    float v = acc[mb][nb][r] + bv;
                    v = v > 0.f ? v : 0.f;
                    if (OUT_F32)
                        ((float*)outv)[(size_t)grow * D + n] = v;
                    else
                        ((__hip_bfloat16*)outv)[(size_t)grow * D + n] =
                            __float2bfloat16(v);
                }
            }
        }
    }
}

extern "C" void kernel_launch(void* const* d_in, const int* in_sizes, int n_in,
                              void* d_out, int out_size, void* d_ws, size_t ws_size,
                              hipStream_t stream) {
    const float* x    = (const float*)d_in[0];
    const int*   ei   = (const int*)d_in[1];
    const float* attr = (const float*)d_in[2];
    const float* Wf   = (const float*)d_in[3];
    const float* bf   = (const float*)d_in[4];
    const float* cw   = (const float*)d_in[5];  // [3][2][128][128]
    const float* cr   = (const float*)d_in[6];  // [3][128][128]
    const float* cb   = (const float*)d_in[7];  // [3][128]
    const int* src  = ei;
    const int* dstv = ei + NE;

    // workspace layout (bytes)
    char* p = (char*)d_ws;
    __hip_bfloat16* h0   = (__hip_bfloat16*)p; p += (size_t)NN * D * 2;
    __hip_bfloat16* h1   = (__hip_bfloat16*)p; p += (size_t)NN * D * 2;
    __hip_bfloat16* aggb = (__hip_bfloat16*)p; p += (size_t)2 * NN * D * 2;
    __hip_bfloat16* wt   = (__hip_bfloat16*)p; p += (size_t)NWT * 2;
    float* inv  = (float*)p;                p += (size_t)2 * NN * 4;
    int*   cnt  = (int*)p;                  p += (size_t)2 * NN * 4;
    int*   off  = (int*)p;                  p += (size_t)2 * NN * 4;
    int*   cur  = (int*)p;                  p += (size_t)2 * NN * 4;
    int*   srcs = (int*)p;                  p += (size_t)NE * 4;
    int*   total= (int*)p;

    float* outp = (float*)d_out;

    // ---- layer-invariant preprocessing ----
    hipMemsetAsync(cnt, 0, (size_t)2 * NN * sizeof(int), stream);
    hipMemsetAsync(total, 0, sizeof(int), stream);
    k_pre1<<<NEB + NWB, 256, 0, stream>>>(attr, dstv, cnt, Wf, cw, cr, wt);
    k_pre2<<<(NN + 255) / 256, 256, 0, stream>>>(cnt, inv, off, cur, total);
    k_fill<<<NEB, 256, 0, stream>>>(attr, src, dstv, cur, srcs, NE);

    // input projection (f32 x read directly)
    k_gemm_proj<<<(NN + 127) / 128, 256, 0, stream>>>(x, wt, bf, h0, NN);

    const int gblocks = (NN + BM - 1) / BM;
    const int ablocks = (NN * 64 + 255) / 256;      // one wave per node
    for (int l = 0; l < 3; ++l) {
        const __hip_bfloat16* hin = (l == 1) ? h1 : h0;
        k_aggregate<<<ablocks, 256, 0, stream>>>(hin, srcs, off, cnt, inv, aggb);
        const __hip_bfloat16* wl = wt + 16384 + (size_t)l * 49152;
        const float* bl = cb + (size_t)l * D;
        if (l == 2) {
            k_gemm_mfma<true><<<gblocks, 256, 0, stream>>>(
                hin, 128, aggb, 256, aggb + 128, 256, wl, bl, outp, NN);
        } else {
            __hip_bfloat16* hout = (l == 0) ? h1 : h0;
            k_gemm_mfma<false><<<gblocks, 256, 0, stream>>>(
                hin, 128, aggb, 256, aggb + 128, 256, wl, bl, hout, NN);
        }
    }
}

// Round 10
// 230.191 us; speedup vs baseline: 1.2574x; 1.1691x over previous
//
#include <hip/hip_runtime.h>
#include <hip/hip_bf16.h>

#define NN 50000
#define NE 600000
#define D 128
#define NREL 2
#define BM 128

typedef __attribute__((ext_vector_type(8))) short bf16x8;   // 8 bf16 (4 VGPRs)
typedef __attribute__((ext_vector_type(4))) float f32x4;    // 4 fp32 acc
typedef __attribute__((ext_vector_type(2))) float f32x2;    // packed pair

__device__ __forceinline__ float bf2f(short s) {
    return __uint_as_float(((unsigned int)(unsigned short)s) << 16);
}
__device__ __forceinline__ bf16x8 pack_bf8(const float* a) {
    union { bf16x8 v; __hip_bfloat162 h2[4]; } o;
#pragma unroll
    for (int i = 0; i < 4; i++)
        o.h2[i] = __float22bfloat162_rn(make_float2(a[2 * i], a[2 * i + 1]));
    return o.v;
}

#define NEB ((NE + 255) / 256)          // edge blocks
#define NWT (16384 + 3 * 49152)         // wt elements
#define NWB ((NWT + 255) / 256)         // prep_w blocks

// ---------------- fused: edge count (blocks < NEB) + weight prep (rest) ------
// bucket key = dst*2 + rel (node-major, rel minor)
// wt[0:16384)                  : proj  Wtp[n][k] = Wf[k][n]          (K=128)
// wt[16384 + l*49152 + n*384+k]: layer l, k<128 root, <256 W0, else W1
__global__ void k_pre1(const float* __restrict__ attr,
                       const int* __restrict__ dst,
                       int* __restrict__ cnt,
                       const float* __restrict__ Wf,
                       const float* __restrict__ cw,
                       const float* __restrict__ cr,
                       __hip_bfloat16* __restrict__ wt) {
    if (blockIdx.x < NEB) {
        int i = blockIdx.x * blockDim.x + threadIdx.x;
        if (i >= NE) return;
        float2 a = reinterpret_cast<const float2*>(attr)[i];
        int r = (a.y > a.x) ? 1 : 0;   // argmax, first-index tiebreak
        atomicAdd(&cnt[dst[i] * 2 + r], 1);
    } else {
        int idx = (blockIdx.x - NEB) * blockDim.x + threadIdx.x;
        if (idx >= NWT) return;
        float v;
        if (idx < 16384) {
            int n = idx >> 7, k = idx & 127;
            v = Wf[k * 128 + n];
        } else {
            int j = idx - 16384;
            int l = j / 49152; j %= 49152;
            int n = j / 384, k = j % 384;
            if (k < 128)      v = cr[((size_t)l * 128 + k) * 128 + n];
            else if (k < 256) v = cw[((size_t)(l * 2 + 0) * 128 + (k - 128)) * 128 + n];
            else              v = cw[((size_t)(l * 2 + 1) * 128 + (k - 256)) * 128 + n];
        }
        wt[idx] = __float2bfloat16(v);
    }
}

// ---------------- inv + per-NODE bucket allocator ----------------------------
// One thread per node: allocates c0+c1 contiguous slots; bucket 2n at o,
// bucket 2n+1 at o+c0. So each node's two relation buckets are adjacent.
__global__ void k_pre2(const int* __restrict__ cnt, float* __restrict__ inv,
                       int* __restrict__ off, int* __restrict__ cur,
                       int* __restrict__ total) {
    int i = blockIdx.x * blockDim.x + threadIdx.x;
    if (i >= NN) return;
    int c0 = cnt[2 * i], c1 = cnt[2 * i + 1];
    inv[2 * i]     = 1.0f / (float)(c0 > 1 ? c0 : 1);
    inv[2 * i + 1] = 1.0f / (float)(c1 > 1 ? c1 : 1);
    int o = atomicAdd(total, c0 + c1);   // wave-coalesced by atomic optimizer
    off[2 * i] = o;       cur[2 * i] = o;
    off[2 * i + 1] = o + c0; cur[2 * i + 1] = o + c0;
}

// ---------------- fill CSR: srcs[pos] = src[e], bucketed by (dst,rel) --------
__global__ void k_fill(const float* __restrict__ attr,
                       const int* __restrict__ src, const int* __restrict__ dst,
                       int* __restrict__ cursor, int* __restrict__ srcs, int E) {
    int i = blockIdx.x * blockDim.x + threadIdx.x;
    if (i >= E) return;
    float2 a = reinterpret_cast<const float2*>(attr)[i];
    int r = (a.y > a.x) ? 1 : 0;
    int pos = atomicAdd(&cursor[dst[i] * 2 + r], 1);
    srcs[pos] = src[i];
}

// ---------------- aggregation: one 16-lane group per NODE, 4 nodes/wave ------
// Group g owns node wid*4+g; its 16 lanes cover the full 256B row (16B/lane).
// Loop bound cmax = max(c01) over the 4 groups -> wave-uniform, so every
// __shfl runs with all 64 lanes active (R5 lesson). Relation mask AND 1/deg
// fold into a per-edge scalar weight -> packed f32x2 fma accumulate
// (v_pk_fma_f32), ~2 VALU/element. NO cross-group reduce; stores are 4
// consecutive nodes = 1KB contiguous per wave.
__global__ __launch_bounds__(256)
void k_aggregate(const __hip_bfloat16* __restrict__ h,
                 const int* __restrict__ srcs,
                 const int* __restrict__ off, const int* __restrict__ cnt,
                 const float* __restrict__ inv,
                 __hip_bfloat16* __restrict__ agg) {
    int wid = (blockIdx.x * blockDim.x + threadIdx.x) >> 6;   // wave id
    int lane = threadIdx.x & 63;
    int nb = wid * 4;
    if (nb >= NN) return;                  // whole-wave uniform (NN%4==0)
    const int g = lane >> 4, l16 = lane & 15;
    int node = nb + g;
    bool nv = node < NN;
    int nn = nv ? node : (NN - 1);

    int st  = off[2 * nn];
    int c0  = nv ? cnt[2 * nn] : 0;
    int c01 = c0 + (nv ? cnt[2 * nn + 1] : 0);
    float i0 = inv[2 * nn], i1 = inv[2 * nn + 1];

    int sv = (l16 < c01) ? srcs[st + l16] : 0;   // group-coalesced index load

    int cm = c01;                                 // wave max of c01
    cm = max(cm, __shfl_xor(cm, 16));
    cm = max(cm, __shfl_xor(cm, 32));

    f32x2 a0[4], a1[4];
#pragma unroll
    for (int p = 0; p < 4; p++) { a0[p] = (f32x2)(0.f); a1[p] = (f32x2)(0.f); }

    const char* hb = (const char*)h;
    for (int j = 0; j < cm; j += 4) {            // wave-uniform trip count
        int s[4]; float w0[4], w1[4];
#pragma unroll
        for (int q = 0; q < 4; ++q) {
            int jj = j + q;
            int t = __shfl(sv, (lane & 48) + (jj & 15));  // full-exec shfl
            s[q] = t;
            if (jj >= 16 && jj < c01) s[q] = srcs[st + jj];  // rare hub path
            if (jj >= c01) s[q] = 0;             // clamp: row 0 valid, L1-hot
            w0[q] = (jj < c0) ? i0 : 0.f;
            w1[q] = (jj >= c0 && jj < c01) ? i1 : 0.f;
        }
        uint4 v[4];
#pragma unroll
        for (int q = 0; q < 4; ++q)              // 4 independent gathers/lane
            v[q] = *reinterpret_cast<const uint4*>(
                hb + (size_t)s[q] * 256 + l16 * 16);
#pragma unroll
        for (int q = 0; q < 4; ++q) {
            f32x2 w0v = {w0[q], w0[q]}, w1v = {w1[q], w1[q]};
            unsigned uu[4] = {v[q].x, v[q].y, v[q].z, v[q].w};
#pragma unroll
            for (int p = 0; p < 4; ++p) {
                f32x2 val;
                val.x = __uint_as_float(uu[p] << 16);
                val.y = __uint_as_float(uu[p] & 0xffff0000u);
                a0[p] += val * w0v;              // v_pk_fma_f32
                a1[p] += val * w1v;
            }
        }
    }

    if (!nv) return;
    float t0[8], t1[8];
#pragma unroll
    for (int p = 0; p < 4; p++) {
        t0[2 * p] = a0[p].x; t0[2 * p + 1] = a0[p].y;
        t1[2 * p] = a1[p].x; t1[2 * p + 1] = a1[p].y;
    }
    __hip_bfloat16* dp = agg + (size_t)node * 256;
    *reinterpret_cast<bf16x8*>(dp + l16 * 8)       = pack_bf8(t0);
    *reinterpret_cast<bf16x8*>(dp + 128 + l16 * 8) = pack_bf8(t1);
}

// ---------------- proj GEMM: h0 = relu(x_f32 @ Wtp^T + bf), bf16 out ---------
__global__ __launch_bounds__(256)
void k_gemm_proj(const float* __restrict__ X,
                 const __hip_bfloat16* __restrict__ Wt,   // [128][128]
                 const float* __restrict__ bias,
                 __hip_bfloat16* __restrict__ out, int N) {
    __shared__ uint4 sB4[1024];            // 16 KB
    char* sB = (char*)sB4;
    const int tid = threadIdx.x;
    const int w = tid >> 6;
    const int l16 = tid & 15, lg = (tid & 63) >> 4;

    f32x4 acc[2][8];
#pragma unroll
    for (int m = 0; m < 2; m++)
#pragma unroll
        for (int n = 0; n < 8; n++) acc[m][n] = (f32x4)(0.f);

    const int row0 = blockIdx.x * 128;
#pragma unroll
    for (int kb = 0; kb < 2; ++kb) {
        bf16x8 afr[2][2];
#pragma unroll
        for (int mb = 0; mb < 2; ++mb)
#pragma unroll
            for (int kk = 0; kk < 2; ++kk) {
                int r = row0 + w * 32 + mb * 16 + l16;
                if (r >= N) r = N - 1;
                const float* p = X + (size_t)r * D + kb * 64 + kk * 32 + lg * 8;
                float4 u0 = reinterpret_cast<const float4*>(p)[0];
                float4 u1 = reinterpret_cast<const float4*>(p)[1];
                float t[8] = {u0.x, u0.y, u0.z, u0.w, u1.x, u1.y, u1.z, u1.w};
                afr[mb][kk] = pack_bf8(t);
            }
        __syncthreads();
        {
            int trow = tid >> 3, tb = (tid & 7) * 16;
#pragma unroll
            for (int p = 0; p < 4; ++p) {
                int rr = trow + p * 32;
                uint4 v = *reinterpret_cast<const uint4*>(
                    (const char*)(Wt + (size_t)rr * 128 + kb * 64) + tb);
                *reinterpret_cast<uint4*>(sB + rr * 128 + (tb ^ ((rr & 7) << 4))) = v;
            }
        }
        __syncthreads();
#pragma unroll
        for (int kk = 0; kk < 2; ++kk)
#pragma unroll
            for (int nb = 0; nb < 8; ++nb) {
                int brow = nb * 16 + l16;
                int bcol = kk * 64 + lg * 16;
                bf16x8 bfr = *reinterpret_cast<const bf16x8*>(
                    sB + brow * 128 + (bcol ^ ((brow & 7) << 4)));
                acc[0][nb] = __builtin_amdgcn_mfma_f32_16x16x32_bf16(
                    afr[0][kk], bfr, acc[0][nb], 0, 0, 0);
                acc[1][nb] = __builtin_amdgcn_mfma_f32_16x16x32_bf16(
                    afr[1][kk], bfr, acc[1][nb], 0, 0, 0);
            }
    }
#pragma unroll
    for (int nb = 0; nb < 8; ++nb) {
        int n = nb * 16 + l16;
        float bv = bias[n];
#pragma unroll
        for (int mb = 0; mb < 2; ++mb)
#pragma unroll
            for (int r = 0; r < 4; ++r) {
                int grow = row0 + w * 32 + mb * 16 + lg * 4 + r;
                if (grow < N) {
                    float v = acc[mb][nb][r] + bv;
                    v = v > 0.f ? v : 0.f;
                    out[(size_t)grow * D + n] = __float2bfloat16(v);
                }
            }
    }
}

// ---------------- MFMA GEMM: out = relu([A0|A1|A2] @ Wt^T + bias) ------------
// Per-chunk row stride (elements): hin is 128, agg (interleaved) is 256.
template <bool OUT_F32>
__global__ __launch_bounds__(256)
void k_gemm_mfma(const __hip_bfloat16* __restrict__ A0, int sA0,
                 const __hip_bfloat16* __restrict__ A1, int sA1,
                 const __hip_bfloat16* __restrict__ A2, int sA2,
                 const __hip_bfloat16* __restrict__ Wt,   // [128][384]
                 const float* __restrict__ bias,
                 void* __restrict__ outv, int N) {
    __shared__ uint4 sB4[1024];            // 16 KB
    char* sB = (char*)sB4;
    const int tid = threadIdx.x;
    const int w = tid >> 6;
    const int l16 = tid & 15, lg = (tid & 63) >> 4;
    const __hip_bfloat16* As[3] = {A0, A1, A2};
    const int strides[3] = {sA0, sA1, sA2};

    f32x4 acc[2][8];
#pragma unroll
    for (int m = 0; m < 2; m++)
#pragma unroll
        for (int n = 0; n < 8; n++) acc[m][n] = (f32x4)(0.f);

    const size_t row0 = (size_t)blockIdx.x * BM;
#pragma unroll
    for (int kb = 0; kb < 6; ++kb) {
        const __hip_bfloat16* Ac = As[kb >> 1];
        const int strideC = strides[kb >> 1];
        const int koff = (kb & 1) * 64;
        bf16x8 afr[2][2];
#pragma unroll
        for (int mb = 0; mb < 2; ++mb)
#pragma unroll
            for (int kk = 0; kk < 2; ++kk) {
                int r = (int)row0 + w * 32 + mb * 16 + l16;
                if (r >= N) r = N - 1;              // clamped; store-guarded later
                afr[mb][kk] = *reinterpret_cast<const bf16x8*>(
                    Ac + (size_t)r * strideC + koff + kk * 32 + lg * 8);
            }
        __syncthreads();   // previous kb's sB reads complete
        {
            int trow = tid >> 3;
            int tb = (tid & 7) * 16;               // byte col within 128B row
#pragma unroll
            for (int p = 0; p < 4; ++p) {
                int rr = trow + p * 32;
                uint4 v = *reinterpret_cast<const uint4*>(
                    (const char*)(Wt + (size_t)rr * 384 + kb * 64) + tb);
                *reinterpret_cast<uint4*>(sB + rr * 128 + (tb ^ ((rr & 7) << 4))) = v;
            }
        }
        __syncthreads();
#pragma unroll
        for (int kk = 0; kk < 2; ++kk) {
#pragma unroll
            for (int nb = 0; nb < 8; ++nb) {
                int brow = nb * 16 + l16;
                int bcol = kk * 64 + lg * 16;
                bf16x8 bfr = *reinterpret_cast<const bf16x8*>(
                    sB + brow * 128 + (bcol ^ ((brow & 7) << 4)));
                acc[0][nb] = __builtin_amdgcn_mfma_f32_16x16x32_bf16(
                    afr[0][kk], bfr, acc[0][nb], 0, 0, 0);
                acc[1][nb] = __builtin_amdgcn_mfma_f32_16x16x32_bf16(
                    afr[1][kk], bfr, acc[1][nb], 0, 0, 0);
            }
        }
    }
#pragma unroll
    for (int nb = 0; nb < 8; ++nb) {
        int n = nb * 16 + l16;
        float bv = bias[n];
#pragma unroll
        for (int mb = 0; mb < 2; ++mb) {
#pragma unroll
            for (int r = 0; r < 4; ++r) {
                long grow = (long)row0 + w * 32 + mb * 16 + lg * 4 + r;
                if (grow < N) {
                    float v = acc[mb][nb][r] + bv;
                    v = v > 0.f ? v : 0.f;
                    if (OUT_F32)
                        ((float*)outv)[(size_t)grow * D + n] = v;
                    else
                        ((__hip_bfloat16*)outv)[(size_t)grow * D + n] =
                            __float2bfloat16(v);
                }
            }
        }
    }
}

extern "C" void kernel_launch(void* const* d_in, const int* in_sizes, int n_in,
                              void* d_out, int out_size, void* d_ws, size_t ws_size,
                              hipStream_t stream) {
    const float* x    = (const float*)d_in[0];
    const int*   ei   = (const int*)d_in[1];
    const float* attr = (const float*)d_in[2];
    const float* Wf   = (const float*)d_in[3];
    const float* bf   = (const float*)d_in[4];
    const float* cw   = (const float*)d_in[5];  // [3][2][128][128]
    const float* cr   = (const float*)d_in[6];  // [3][128][128]
    const float* cb   = (const float*)d_in[7];  // [3][128]
    const int* src  = ei;
    const int* dstv = ei + NE;

    // workspace layout (bytes)
    char* p = (char*)d_ws;
    __hip_bfloat16* h0   = (__hip_bfloat16*)p; p += (size_t)NN * D * 2;
    __hip_bfloat16* h1   = (__hip_bfloat16*)p; p += (size_t)NN * D * 2;
    __hip_bfloat16* aggb = (__hip_bfloat16*)p; p += (size_t)2 * NN * D * 2;
    __hip_bfloat16* wt   = (__hip_bfloat16*)p; p += (size_t)NWT * 2;
    float* inv  = (float*)p;                p += (size_t)2 * NN * 4;
    int*   cnt  = (int*)p;                  p += (size_t)2 * NN * 4;
    int*   off  = (int*)p;                  p += (size_t)2 * NN * 4;
    int*   cur  = (int*)p;                  p += (size_t)2 * NN * 4;
    int*   srcs = (int*)p;                  p += (size_t)NE * 4;
    int*   total= (int*)p;

    float* outp = (float*)d_out;

    // ---- layer-invariant preprocessing ----
    hipMemsetAsync(cnt, 0, (size_t)2 * NN * sizeof(int), stream);
    hipMemsetAsync(total, 0, sizeof(int), stream);
    k_pre1<<<NEB + NWB, 256, 0, stream>>>(attr, dstv, cnt, Wf, cw, cr, wt);
    k_pre2<<<(NN + 255) / 256, 256, 0, stream>>>(cnt, inv, off, cur, total);
    k_fill<<<NEB, 256, 0, stream>>>(attr, src, dstv, cur, srcs, NE);

    // input projection (f32 x read directly)
    k_gemm_proj<<<(NN + 127) / 128, 256, 0, stream>>>(x, wt, bf, h0, NN);

    const int gblocks = (NN + BM - 1) / BM;
    const int ablocks = ((NN + 3) / 4 * 64 + 255) / 256;  // 16-lane group/node
    for (int l = 0; l < 3; ++l) {
        const __hip_bfloat16* hin = (l == 1) ? h1 : h0;
        k_aggregate<<<ablocks, 256, 0, stream>>>(hin, srcs, off, cnt, inv, aggb);
        const __hip_bfloat16* wl = wt + 16384 + (size_t)l * 49152;
        const float* bl = cb + (size_t)l * D;
        if (l == 2) {
            k_gemm_mfma<true><<<gblocks, 256, 0, stream>>>(
                hin, 128, aggb, 256, aggb + 128, 256, wl, bl, outp, NN);
        } else {
            __hip_bfloat16* hout = (l == 0) ? h1 : h0;
            k_gemm_mfma<false><<<gblocks, 256, 0, stream>>>(
                hin, 128, aggb, 256, aggb + 128, 256, wl, bl, hout, NN);
        }
    }
}